// Round 1
// baseline (53.729 us; speedup 1.0000x reference)
//
#include <hip/hip_runtime.h>
#include <math.h>

#define B_  64
#define C_  768
#define HW_ 1024          // 32*32
#define NCLS 100
#define E_  16
#define K_  2
#define FAN (C_ + NCLS)   // 868

// ---------------- Kernel 1: adaptive avg pool (mean over 32x32) ----------------
// One wave (64 lanes) per (b,c) row of 1024 contiguous floats.
__global__ __launch_bounds__(256) void pool_kernel(const float* __restrict__ x,
                                                   float* __restrict__ pooled) {
    const int gtid = blockIdx.x * blockDim.x + threadIdx.x;
    const int row  = gtid >> 6;          // wave id == row (b*C + c)
    const int lane = threadIdx.x & 63;
    if (row >= B_ * C_) return;

    const float4* p = reinterpret_cast<const float4*>(x + (size_t)row * HW_);
    float4 a = p[lane];
    float4 b = p[lane + 64];
    float4 c = p[lane + 128];
    float4 d = p[lane + 192];
    float s = (a.x + a.y + a.z + a.w) + (b.x + b.y + b.z + b.w)
            + (c.x + c.y + c.z + c.w) + (d.x + d.y + d.z + d.w);

    #pragma unroll
    for (int off = 32; off > 0; off >>= 1) s += __shfl_down(s, off);

    if (lane == 0) pooled[row] = s * (1.0f / (float)HW_);
}

// ---------------- Kernel 2: softmax + gate + top-2 + outputs ----------------
// One block per batch element. 256 threads = 4 waves.
__global__ __launch_bounds__(256) void router_kernel(const float* __restrict__ pooled,
                                                     const float* __restrict__ task_cls,
                                                     const float* __restrict__ Wm,
                                                     const float* __restrict__ bias,
                                                     float* __restrict__ out) {
    const int b   = blockIdx.x;
    const int tid = threadIdx.x;
    const int lane = tid & 63;
    const int wav  = tid >> 6;

    __shared__ float fused[FAN];
    __shared__ float logits_s[E_];
    __shared__ int   sel_s[K_];

    // pooled image features -> fused[0..767]
    for (int i = tid; i < C_; i += 256) fused[i] = pooled[b * C_ + i];

    // softmax(task_cls[b]) -> fused[768..867]; wave 0 handles all 100 elems
    if (tid < 64) {
        float v1 = task_cls[b * NCLS + tid];
        bool has2 = (tid + 64) < NCLS;
        float v2 = has2 ? task_cls[b * NCLS + tid + 64] : -INFINITY;
        float m = fmaxf(v1, v2);
        #pragma unroll
        for (int off = 32; off > 0; off >>= 1) m = fmaxf(m, __shfl_down(m, off));
        m = __shfl(m, 0);
        float e1 = __expf(v1 - m);
        float e2 = has2 ? __expf(v2 - m) : 0.0f;
        float s = e1 + e2;
        #pragma unroll
        for (int off = 32; off > 0; off >>= 1) s += __shfl_down(s, off);
        s = __shfl(s, 0);
        float inv = 1.0f / s;
        fused[C_ + tid] = e1 * inv;
        if (has2) fused[C_ + tid + 64] = e2 * inv;
    }
    __syncthreads();

    // 16 expert dot products: wave w handles experts 4w..4w+3
    #pragma unroll
    for (int q = 0; q < 4; ++q) {
        const int e = wav * 4 + q;
        const float* wr = Wm + (size_t)e * FAN;
        float acc = 0.0f;
        for (int j = lane; j < FAN; j += 64) acc += fused[j] * wr[j];
        #pragma unroll
        for (int off = 32; off > 0; off >>= 1) acc += __shfl_down(acc, off);
        if (lane == 0) {
            float lg = acc + bias[e];
            logits_s[e] = lg;
            out[b * E_ + e] = lg;                 // router_logits [B,E] @ 0
        }
    }
    __syncthreads();

    // top-2 (strict > keeps lowest index on ties, matching lax.top_k)
    if (tid == 0) {
        float m1 = -INFINITY, m2 = -INFINITY;
        int i1 = 0, i2 = 0;
        #pragma unroll
        for (int e = 0; e < E_; ++e) {
            float v = logits_s[e];
            if (v > m1) { m2 = m1; i2 = i1; m1 = v; i1 = e; }
            else if (v > m2) { m2 = v; i2 = e; }
        }
        // renormalized softmax pair: w0 = p1/(p1+p2) = 1/(1+exp(l2-l1))
        float r = expf(m2 - m1);
        float w0 = 1.0f / (1.0f + r);
        float w1 = r * w0;
        out[1024 + b * K_ + 0] = w0;              // router_weights [B,K] @ 1024
        out[1024 + b * K_ + 1] = w1;
        out[1152 + b * K_ + 0] = (float)i1;       // selected_experts [B,K] @ 1152
        out[1152 + b * K_ + 1] = (float)i2;
        sel_s[0] = i1; sel_s[1] = i2;
    }
    __syncthreads();

    // expert_mask [E,K,B] @ 1280 : flat e*K*B + k*B + b
    if (tid < E_ * K_) {
        int e = tid >> 1;
        int k = tid & 1;
        out[1280 + e * (K_ * B_) + k * B_ + b] = (sel_s[k] == e) ? 1.0f : 0.0f;
    }
}

extern "C" void kernel_launch(void* const* d_in, const int* in_sizes, int n_in,
                              void* d_out, int out_size, void* d_ws, size_t ws_size,
                              hipStream_t stream) {
    const float* hidden   = (const float*)d_in[0];  // [64,768,32,32]
    const float* task_cls = (const float*)d_in[1];  // [64,100]
    const float* Wm       = (const float*)d_in[2];  // [16,868]
    const float* bias     = (const float*)d_in[3];  // [16]
    float* out = (float*)d_out;
    float* pooled = (float*)d_ws;                   // B*C floats = 192 KiB

    const int rows = B_ * C_;                       // 49152 waves
    const int blocks = rows / 4;                    // 4 waves per 256-thread block
    pool_kernel<<<blocks, 256, 0, stream>>>(hidden, pooled);
    router_kernel<<<B_, 256, 0, stream>>>(pooled, task_cls, Wm, bias, out);
}